// Round 4
// baseline (12517.750 us; speedup 1.0000x reference)
//
#include <hip/hip_runtime.h>
#include <math.h>

#define Lq 128
#define Bq 32
#define Hq 512
#define VOC 32000

typedef float f32x4 __attribute__((ext_vector_type(4)));

// ---------------- embedding gather: x_tm[t][b][e] ----------------
__global__ __launch_bounds__(256) void embed_k(const int* __restrict__ word,
                                               const float* __restrict__ emb,
                                               float* __restrict__ x_tm) {
  int r = blockIdx.x * 2 + (threadIdx.x >> 7);   // row = t*32+b, 0..4095
  int e = threadIdx.x & 127;
  int t = r >> 5, b = r & 31;
  int w = word[b * Lq + t];
  x_tm[(size_t)r * 128 + e] = emb[(size_t)w * 128 + e];
}

// ---------------- generic fp32 GEMM: C[M][N] = A[M][K] @ W[N][K]^T + bias ----------------
__global__ __launch_bounds__(256) void gemm_k(const float* __restrict__ A,
                                              const float* __restrict__ W,
                                              const float* __restrict__ bias,
                                              float* __restrict__ C,
                                              int N, int K, int relu) {
  __shared__ float As[32][132];
  __shared__ float Ws[32][132];
  int tid = threadIdx.x;
  int tx = tid & 15, ty = tid >> 4;
  int rb = blockIdx.y * 128, cb = blockIdx.x * 128;
  float acc[8][8];
#pragma unroll
  for (int i = 0; i < 8; ++i)
#pragma unroll
    for (int j = 0; j < 8; ++j) acc[i][j] = 0.f;

  for (int k0 = 0; k0 < K; k0 += 32) {
#pragma unroll
    for (int j = 0; j < 4; ++j) {
      int f = tid + 256 * j;
      int r = f >> 3, kq = (f & 7) * 4;
      float4 va = *(const float4*)&A[(size_t)(rb + r) * K + k0 + kq];
      As[kq + 0][r] = va.x; As[kq + 1][r] = va.y; As[kq + 2][r] = va.z; As[kq + 3][r] = va.w;
      float4 vw = *(const float4*)&W[(size_t)(cb + r) * K + k0 + kq];
      Ws[kq + 0][r] = vw.x; Ws[kq + 1][r] = vw.y; Ws[kq + 2][r] = vw.z; Ws[kq + 3][r] = vw.w;
    }
    __syncthreads();
#pragma unroll 8
    for (int kk = 0; kk < 32; ++kk) {
      float a[8], w[8];
      *(float4*)&a[0] = *(const float4*)&As[kk][ty * 8];
      *(float4*)&a[4] = *(const float4*)&As[kk][ty * 8 + 4];
      *(float4*)&w[0] = *(const float4*)&Ws[kk][tx * 8];
      *(float4*)&w[4] = *(const float4*)&Ws[kk][tx * 8 + 4];
#pragma unroll
      for (int i = 0; i < 8; ++i)
#pragma unroll
        for (int j = 0; j < 8; ++j)
          acc[i][j] = fmaf(a[i], w[j], acc[i][j]);
    }
    __syncthreads();
  }
#pragma unroll
  for (int i = 0; i < 8; ++i) {
    int r = rb + ty * 8 + i;
#pragma unroll
    for (int j = 0; j < 8; j += 4) {
      int c = cb + tx * 8 + j;
      float4 o;
      o.x = acc[i][j + 0] + bias[c + 0];
      o.y = acc[i][j + 1] + bias[c + 1];
      o.z = acc[i][j + 2] + bias[c + 2];
      o.w = acc[i][j + 3] + bias[c + 3];
      if (relu) {
        o.x = fmaxf(o.x, 0.f); o.y = fmaxf(o.y, 0.f);
        o.z = fmaxf(o.z, 0.f); o.w = fmaxf(o.w, 0.f);
      }
      *(float4*)&C[(size_t)r * N + c] = o;
    }
  }
}

// ---------------- persistent LSTM layer: 256 WGs, flag-sync per step ----------------
// wg>>7 = dir, (wg&127)*4 = h-col base. H double-buffered by step parity (global).
// Cross-XCD exchange: AGENT-scope atomics (sc0 sc1 -> served by coherent L3).
// __syncthreads() before flag publish drains vmcnt -> h stores are at the
// coherence point before the flag becomes visible.
// LDS (dynamic): h_s[32][516] | w_s[16][516] | red[32][16][17] | g2[32][17]
#define HSP 516
#define LSTM_DYN_LDS 136064

__global__ __launch_bounds__(256, 1) void lstm_persist(
    const float* __restrict__ GX, const float* __restrict__ Whh,
    const float* __restrict__ mask, float* Hst,
    float* __restrict__ seq_out, int* flags, int layer) {
  extern __shared__ float smem[];
  float* h_s = smem;                  // 32*516
  float* w_s = h_s + 32 * HSP;        // 16*516
  float* red = w_s + 16 * HSP;        // 32*16*17 = 8704
  float* g2  = red + 8704;            // 32*17

  int tid = threadIdx.x;
  int wg = blockIdx.x;
  int d = wg >> 7;
  int hcB = (wg & 127) * 4;
  int base = layer * 128;

  int ks = tid & 15;          // k-split 0..15
  int tile = tid >> 4;        // 0..15
  int q = tile & 7;           // b-set {q, q+8, q+16, q+24}
  int c0 = (tile >> 3) * 8;   // gate-col group {c0..c0+7}

  // ---- stage Whh rows once: local c -> global row d*2048 + (c>>2)*512 + hcB + (c&3)
#pragma unroll
  for (int j = 0; j < 8; ++j) {
    int f = tid + 256 * j;
    int c = f >> 7, k4 = (f & 127) * 4;
    int grow = d * 2048 + (c >> 2) * 512 + hcB + (c & 3);
    f32x4 v = *(const f32x4*)&Whh[(size_t)grow * 512 + k4];
    *(f32x4*)&w_s[c * HSP + k4] = v;
  }

  float creg = 0.f;           // cell state for (b = tid>>2, hcl = tid&3), tid<128

  for (int t = 0; t < 128; ++t) {
    int tdata = d ? (127 - t) : t;
    // ---- wait for all 256 WGs to have published step t-1
    if (t > 0) {
      int tgt = base + t;
      int spin = 0;
      while (__hip_atomic_load(&flags[tid], __ATOMIC_RELAXED,
                               __HIP_MEMORY_SCOPE_AGENT) < tgt) {
        if (++spin > 2000000) break;   // bounded: fail visibly, never hang
        __builtin_amdgcn_s_sleep(2);
      }
    }
    __syncthreads();   // all 256 flags collectively verified

    // ---- stage h_{t-1} (32 x 512) via agent-scope loads (coherent at L3)
    {
      const float* Hprev = Hst + (t & 1) * 32768 + d * 16384;
#pragma unroll 16
      for (int j = 0; j < 64; ++j) {
        int f = tid + 256 * j;          // 0..16383
        int b = f >> 9, k = f & 511;
        float v = 0.f;
        if (t > 0)
          v = __hip_atomic_load(Hprev + b * 512 + k, __ATOMIC_RELAXED,
                                __HIP_MEMORY_SCOPE_AGENT);
        h_s[b * HSP + k] = v;
      }
    }
    __syncthreads();

    // ---- GEMV: acc[4 b][8 c] over this thread's interleaved k-chunks
    float acc[4][8];
#pragma unroll
    for (int m = 0; m < 4; ++m)
#pragma unroll
      for (int c = 0; c < 8; ++c) acc[m][c] = 0.f;
#pragma unroll
    for (int j = 0; j < 8; ++j) {
      int k0 = 4 * ks + 64 * j;
      f32x4 hv[4], wvv[8];
#pragma unroll
      for (int m = 0; m < 4; ++m) hv[m] = *(const f32x4*)&h_s[(q + 8 * m) * HSP + k0];
#pragma unroll
      for (int c = 0; c < 8; ++c) wvv[c] = *(const f32x4*)&w_s[(c0 + c) * HSP + k0];
#pragma unroll
      for (int m = 0; m < 4; ++m)
#pragma unroll
        for (int c = 0; c < 8; ++c)
#pragma unroll
          for (int kk = 0; kk < 4; ++kk)
            acc[m][c] = fmaf(hv[m][kk], wvv[c][kk], acc[m][c]);
    }
#pragma unroll
    for (int m = 0; m < 4; ++m)
#pragma unroll
      for (int c = 0; c < 8; ++c)
        red[(q + 8 * m) * 272 + (c0 + c) * 17 + ks] = acc[m][c];
    __syncthreads();

    // ---- k-split reduce + GX add
#pragma unroll
    for (int rep = 0; rep < 2; ++rep) {
      int o = tid + 256 * rep;
      int b = o >> 4, c = o & 15;
      float s = 0.f;
#pragma unroll
      for (int kq = 0; kq < 16; ++kq) s += red[b * 272 + c * 17 + kq];
      s += GX[(size_t)(tdata * 32 + b) * 4096 + d * 2048 + (c >> 2) * 512 + hcB + (c & 3)];
      g2[b * 17 + c] = s;
    }
    __syncthreads();

    // ---- cell update (128 threads), publish h (agent scope)
    if (tid < 128) {
      int b = tid >> 2, hcl = tid & 3;
      int hh = hcB + hcl;
      float iv = g2[b * 17 + 0 + hcl], fv = g2[b * 17 + 4 + hcl];
      float gv = g2[b * 17 + 8 + hcl], ov = g2[b * 17 + 12 + hcl];
      float cp = creg;
      float hp = h_s[b * HSP + hh];
      float m = mask[b * Lq + tdata];
      float ig = 1.f / (1.f + expf(-iv));
      float fg = 1.f / (1.f + expf(-fv));
      float gg = tanhf(gv);
      float og = 1.f / (1.f + expf(-ov));
      float cn = fg * cp + ig * gg;
      float hn = og * tanhf(cn);
      float ho = hp + (hn - hp) * m;
      creg = cp + (cn - cp) * m;
      float* Hnext = Hst + ((t + 1) & 1) * 32768 + d * 16384;
      __hip_atomic_store(Hnext + b * 512 + hh, ho, __ATOMIC_RELAXED,
                         __HIP_MEMORY_SCOPE_AGENT);
      seq_out[(size_t)(tdata * 32 + b) * 1024 + d * 512 + hh] = ho;
    }
    __syncthreads();   // drains vmcnt: h stores reach coherence point before flag
    if (tid == 0)
      __hip_atomic_store(&flags[wg], base + t + 1, __ATOMIC_RELAXED,
                         __HIP_MEMORY_SCOPE_AGENT);
  }
}

// ---------------- decoder: fused logits + per-row chunk reductions ----------------
__global__ __launch_bounds__(256) void dec_k(
    const float* __restrict__ hid, const float* __restrict__ w2,
    const float* __restrict__ b2, const int* __restrict__ tgt_word,
    float* __restrict__ part) {
  __shared__ float ht[128][68];
  __shared__ float wt[128][68];
  __shared__ float lg[64][68];
  int tid = threadIdx.x;
  int vb = blockIdx.x, rb = blockIdx.y;
  int r0 = rb * 64, v0 = vb * 512;
#pragma unroll
  for (int j = 0; j < 8; ++j) {
    int f = tid + 256 * j;
    int r = f >> 5, kq = (f & 31) * 4;
    float4 v = *(const float4*)&hid[(size_t)(r0 + r) * 128 + kq];
    ht[kq + 0][r] = v.x; ht[kq + 1][r] = v.y; ht[kq + 2][r] = v.z; ht[kq + 3][r] = v.w;
  }
  float M = -INFINITY, S = 0.f, Tl = 0.f;
  int Iv = 0, tgtv = -1;
  if (tid < 64) {
    int r = r0 + tid, t = r >> 5, b = r & 31;
    tgtv = tgt_word[b * Lq + t];
  }
  int nvt = min(8, (VOC - v0 + 63) >> 6);
  int tx = tid & 15, ty = tid >> 4;
  for (int vt = 0; vt < nvt; ++vt) {
    int vbase = v0 + vt * 64;
    __syncthreads();
#pragma unroll
    for (int j = 0; j < 8; ++j) {
      int f = tid + 256 * j;
      int v = f >> 5, kq = (f & 31) * 4;
      int vg = vbase + v;
      float4 x = make_float4(0.f, 0.f, 0.f, 0.f);
      if (vg < VOC) x = *(const float4*)&w2[(size_t)vg * 128 + kq];
      wt[kq + 0][v] = x.x; wt[kq + 1][v] = x.y; wt[kq + 2][v] = x.z; wt[kq + 3][v] = x.w;
    }
    __syncthreads();
    float acc[4][4];
#pragma unroll
    for (int i = 0; i < 4; ++i)
#pragma unroll
      for (int j = 0; j < 4; ++j) acc[i][j] = 0.f;
#pragma unroll 4
    for (int k = 0; k < 128; ++k) {
      float a[4], w[4];
      *(float4*)a = *(const float4*)&ht[k][ty * 4];
      *(float4*)w = *(const float4*)&wt[k][tx * 4];
#pragma unroll
      for (int i = 0; i < 4; ++i)
#pragma unroll
        for (int j = 0; j < 4; ++j)
          acc[i][j] = fmaf(a[i], w[j], acc[i][j]);
    }
#pragma unroll
    for (int i = 0; i < 4; ++i)
#pragma unroll
      for (int j = 0; j < 4; ++j) {
        int v = vbase + tx * 4 + j;
        lg[ty * 4 + i][tx * 4 + j] = acc[i][j] + (v < VOC ? b2[v] : 0.f);
      }
    __syncthreads();
    if (tid < 64) {
      for (int j = 0; j < 64; ++j) {
        int v = vbase + j;
        if (v >= VOC) break;
        float val = lg[tid][j];
        if (val > M) { S = S * expf(M - val) + 1.f; M = val; Iv = v; }
        else S += expf(val - M);
        if (v == tgtv) Tl = val;
      }
    }
  }
  if (tid < 64) {
    int r = r0 + tid;
    float4 o; o.x = M; o.y = S; o.z = (float)Iv; o.w = Tl;
    *(float4*)&part[((size_t)vb * 4096 + r) * 4] = o;
  }
}

// ---------------- combine chunks per row; write argmax + per-row weighted nll ----------------
__global__ __launch_bounds__(256) void dec_fin_k(
    const float* __restrict__ part, const int* __restrict__ tgt_word,
    const float* __restrict__ cew, float* __restrict__ out,
    float* __restrict__ rowred) {
  int r = blockIdx.x * 256 + threadIdx.x;
  float M = -INFINITY, S = 0.f, If = 0.f;
  for (int ch = 0; ch < 63; ++ch) {
    float4 p = *(const float4*)&part[((size_t)ch * 4096 + r) * 4];
    if (p.x > M) { S = S * expf(M - p.x) + p.y; M = p.x; If = p.z; }
    else S += p.y * expf(p.x - M);
  }
  int t = r >> 5, b = r & 31;
  int tgt = tgt_word[b * Lq + t];
  float Tl = part[((size_t)(tgt >> 9) * 4096 + r) * 4 + 3];
  float lse = M + logf(S);
  float w = cew[tgt];
  out[1 + b * Lq + t] = If;
  rowred[r] = (lse - Tl) * w;
  rowred[4096 + r] = w;
}

__global__ __launch_bounds__(256) void loss_k(const float* __restrict__ rowred,
                                              float* __restrict__ out) {
  __shared__ float s1[256], s2[256];
  float a = 0.f, c = 0.f;
  for (int r = threadIdx.x; r < 4096; r += 256) { a += rowred[r]; c += rowred[4096 + r]; }
  s1[threadIdx.x] = a; s2[threadIdx.x] = c;
  __syncthreads();
  for (int o = 128; o > 0; o >>= 1) {
    if ((int)threadIdx.x < o) { s1[threadIdx.x] += s1[threadIdx.x + o]; s2[threadIdx.x] += s2[threadIdx.x + o]; }
    __syncthreads();
  }
  if (threadIdx.x == 0) out[0] = s1[0] / s2[0];
}

extern "C" void kernel_launch(void* const* d_in, const int* in_sizes, int n_in,
                              void* d_out, int out_size, void* d_ws, size_t ws_size,
                              hipStream_t stream) {
  (void)in_sizes; (void)n_in; (void)out_size; (void)ws_size;
  const int*   inp_word = (const int*)d_in[0];
  const float* inp_mask = (const float*)d_in[1];
  const int*   tgt_word = (const int*)d_in[3];
  const float* emb      = (const float*)d_in[4];
  const float* w_ih0    = (const float*)d_in[5];
  const float* w_hh0    = (const float*)d_in[6];
  const float* b0       = (const float*)d_in[7];
  const float* w_ih     = (const float*)d_in[8];
  const float* w_hh     = (const float*)d_in[9];
  const float* bb       = (const float*)d_in[10];
  const float* dec_w1   = (const float*)d_in[11];
  const float* dec_b1   = (const float*)d_in[12];
  const float* dec_w2   = (const float*)d_in[13];
  const float* dec_b2   = (const float*)d_in[14];
  const float* cew      = (const float*)d_in[15];
  float* out = (float*)d_out;
  float* ws  = (float*)d_ws;

  float* x_tm   = ws;                      // 524288
  float* seqA   = x_tm + 524288;           // 4194304
  float* seqB   = seqA + 4194304;          // 4194304
  float* GX     = seqB + 4194304;          // 16777216
  float* hid    = GX + 16777216;           // 524288
  float* Hst    = hid + 524288;            // 2 parity * 2 dir * 16384 = 65536
  float* Cst    = Hst + 65536;             // 32768 (unused now)
  float* part   = Cst + 32768;             // 63*4096*4 = 1032192
  float* rowred = part + 1032192;          // 8192
  int*   flags  = (int*)(rowred + 8192);   // 256 ints

  // raise dynamic LDS cap for the persistent kernel (idempotent, per-call)
  hipFuncSetAttribute((const void*)lstm_persist,
                      hipFuncAttributeMaxDynamicSharedMemorySize, LSTM_DYN_LDS);

  hipMemsetAsync(flags, 0, 256 * sizeof(int), stream);
  embed_k<<<2048, 256, 0, stream>>>(inp_word, emb, x_tm);

  // ---- layer 0 ----
  gemm_k<<<dim3(32, 32), 256, 0, stream>>>(x_tm, w_ih0, b0, GX, 4096, 128, 0);
  lstm_persist<<<256, 256, LSTM_DYN_LDS, stream>>>(GX, w_hh0, inp_mask, Hst, seqA, flags, 0);

  // ---- layer 1 ----
  gemm_k<<<dim3(32, 32), 256, 0, stream>>>(seqA, w_ih, bb, GX, 4096, 1024, 0);
  lstm_persist<<<256, 256, LSTM_DYN_LDS, stream>>>(GX, w_hh, inp_mask, Hst, seqB, flags, 1);

  // ---- layer 2 ----
  gemm_k<<<dim3(32, 32), 256, 0, stream>>>(seqB, w_ih + (size_t)2 * 2048 * 1024,
                                           bb + 4096, GX, 4096, 1024, 0);
  lstm_persist<<<256, 256, LSTM_DYN_LDS, stream>>>(GX, w_hh + (size_t)2 * 2048 * 512,
                                                   inp_mask, Hst, seqA, flags, 2);

  // ---- decoder ----
  gemm_k<<<dim3(1, 32), 256, 0, stream>>>(seqA, dec_w1, dec_b1, hid, 128, 1024, 1);
  dec_k<<<dim3(63, 64), 256, 0, stream>>>(hid, dec_w2, dec_b2, tgt_word, part);
  dec_fin_k<<<16, 256, 0, stream>>>(part, tgt_word, cew, out, rowred);
  loss_k<<<1, 256, 0, stream>>>(rowred, out);
}